// Round 1
// baseline (300.415 us; speedup 1.0000x reference)
//
#include <hip/hip_runtime.h>
#include <hip/hip_bf16.h>
#include <stdint.h>

typedef __attribute__((ext_vector_type(4))) float f32x4;
typedef __attribute__((ext_vector_type(8))) short bf16x8;
typedef __attribute__((ext_vector_type(4))) uint32_t u32x4;

#define KD 512
#define ND 512

// pack two fp32 -> one u32 holding two bf16 (round-half-away via +0x8000, then
// v_perm_b32 grabs the high 16 bits of each)
__device__ __forceinline__ uint32_t pk_bf16(float lo, float hi) {
  uint32_t ulo = __float_as_uint(lo) + 0x8000u;
  uint32_t uhi = __float_as_uint(hi) + 0x8000u;
  return __builtin_amdgcn_perm(uhi, ulo, 0x07060302u);
}

// Transpose + RNE-convert w (512x512 fp32, w[c][d]) -> wt[d][c] bf16 in d_ws.
__global__ void wt_kernel(const float* __restrict__ w, uint16_t* __restrict__ wt) {
  __shared__ float tile[32][33];
  const int bx = blockIdx.x, by = blockIdx.y;
  const int tx = threadIdx.x, ty = threadIdx.y;  // (32, 8)
#pragma unroll
  for (int i = 0; i < 32; i += 8)
    tile[ty + i][tx] = w[(bx * 32 + ty + i) * ND + by * 32 + tx];
  __syncthreads();
#pragma unroll
  for (int i = 0; i < 32; i += 8) {
    uint32_t u = __float_as_uint(tile[tx][ty + i]);
    uint32_t r = (u + 0x7FFFu + ((u >> 16) & 1u)) >> 16;  // RNE
    wt[(by * 32 + ty + i) * KD + bx * 32 + tx] = (uint16_t)r;
  }
}

// C[m0+u, :] = A[m0+perm(u), :] @ W   (A = x flat 65536x512 fp32, W via wt bf16)
// BM=128 BN=128 BK=32, 4 waves (2x2), wave tile 64x64, 16x16x32 bf16 MFMA.
__global__ __launch_bounds__(256) void gemm_kernel(
    const float* __restrict__ x, const uint16_t* __restrict__ wt,
    float* __restrict__ out) {
  __shared__ uint16_t As[2][128 * 32];
  __shared__ uint16_t Ws[2][128 * 32];

  const int tid = threadIdx.x;
  const int lane = tid & 63;
  const int wid = tid >> 6;
  const int wr = wid >> 1, wc = wid & 1;

  // XCD-aware bijective swizzle: 2048 wgs -> 256 per XCD; nt in low bits so the
  // 4 N-tiles sharing an A-panel run back-to-back on one XCD (A L2-resident).
  const int bid = blockIdx.x;
  const int logical = (bid & 7) * 256 + (bid >> 3);
  const int nt = logical & 3;
  const int mt = logical >> 2;
  const int m0 = mt * 128, n0 = nt * 128;

  // ---- staging assignment: thread -> (row sr, octets sj0, sj0+1) ----
  const int sr = tid >> 1;                 // 0..127
  const int sj0 = (tid & 1) * 2;           // 0 or 2 (8-elem k-octets)
  // patch-expansion permutation folded into the A row address (local to 64-blocks)
  const int aRow = m0 + ((sr & 64) | ((sr & 31) << 1) | ((sr >> 5) & 1));
  const float* aPtr = x + aRow * KD + sj0 * 8;
  const uint16_t* wPtr = wt + (n0 + sr) * KD + sj0 * 8;
  // T2 swizzle: XOR 16B-slot index with (row>>1)&3  (2 lanes/slot -> conflict-free)
  const int swz = (sr >> 1) & 3;
  const int wb0 = sr * 64 + ((sj0 ^ swz) << 4);
  const int wb1 = sr * 64 + (((sj0 + 1) ^ swz) << 4);

  // ---- fragment read offsets (constant across K-steps) ----
  const int fr = lane & 15, fj = lane >> 4;
  int aOff[4], bOff[4];
#pragma unroll
  for (int m = 0; m < 4; ++m) {
    int row = wr * 64 + m * 16 + fr;
    aOff[m] = row * 64 + ((fj ^ ((row >> 1) & 3)) << 4);
    int col = wc * 64 + m * 16 + fr;
    bOff[m] = col * 64 + ((fj ^ ((col >> 1) & 3)) << 4);
  }

  f32x4 acc[4][4];
#pragma unroll
  for (int m = 0; m < 4; ++m)
#pragma unroll
    for (int n = 0; n < 4; ++n) acc[m][n] = (f32x4){0.f, 0.f, 0.f, 0.f};

  // ---- stage K-step 0 into registers ----
  f32x4 a0 = *(const f32x4*)(aPtr + 0);
  f32x4 a1 = *(const f32x4*)(aPtr + 4);
  f32x4 a2 = *(const f32x4*)(aPtr + 8);
  f32x4 a3 = *(const f32x4*)(aPtr + 12);
  u32x4 w0 = *(const u32x4*)(wPtr + 0);
  u32x4 w1 = *(const u32x4*)(wPtr + 8);
  aPtr += 32; wPtr += 32;

#pragma unroll 2
  for (int t = 0; t < 16; ++t) {
    uint16_t* Ab = As[t & 1];
    uint16_t* Wb = Ws[t & 1];
    // pack fp32->bf16 and commit this K-step's tiles to LDS
    u32x4 pa0 = {pk_bf16(a0.x, a0.y), pk_bf16(a0.z, a0.w),
                 pk_bf16(a1.x, a1.y), pk_bf16(a1.z, a1.w)};
    u32x4 pa1 = {pk_bf16(a2.x, a2.y), pk_bf16(a2.z, a2.w),
                 pk_bf16(a3.x, a3.y), pk_bf16(a3.z, a3.w)};
    *(u32x4*)((char*)Ab + wb0) = pa0;
    *(u32x4*)((char*)Ab + wb1) = pa1;
    *(u32x4*)((char*)Wb + wb0) = w0;
    *(u32x4*)((char*)Wb + wb1) = w1;
    __syncthreads();
    // T14: issue next K-step's global loads now; they land under the MFMAs
    if (t < 15) {
      a0 = *(const f32x4*)(aPtr + 0);
      a1 = *(const f32x4*)(aPtr + 4);
      a2 = *(const f32x4*)(aPtr + 8);
      a3 = *(const f32x4*)(aPtr + 12);
      w0 = *(const u32x4*)(wPtr + 0);
      w1 = *(const u32x4*)(wPtr + 8);
      aPtr += 32; wPtr += 32;
    }
    bf16x8 af[4], wf[4];
#pragma unroll
    for (int m = 0; m < 4; ++m) af[m] = *(bf16x8*)((char*)Ab + aOff[m]);
#pragma unroll
    for (int n = 0; n < 4; ++n) wf[n] = *(bf16x8*)((char*)Wb + bOff[n]);
    // operand swap: D[d][m] -> each lane's 4 acc regs = 4 consecutive C columns
#pragma unroll
    for (int m = 0; m < 4; ++m)
#pragma unroll
      for (int n = 0; n < 4; ++n)
        acc[m][n] = __builtin_amdgcn_mfma_f32_16x16x32_bf16(wf[n], af[m],
                                                            acc[m][n], 0, 0, 0);
  }

  // ---- epilogue: float4 stores (lane holds 4 consecutive columns) ----
  const int orow = m0 + wr * 64 + fr;
  const int ocol = n0 + wc * 64 + (fj << 2);
#pragma unroll
  for (int m = 0; m < 4; ++m)
#pragma unroll
    for (int n = 0; n < 4; ++n)
      *(f32x4*)(out + (orow + m * 16) * ND + ocol + n * 16) = acc[m][n];
}

extern "C" void kernel_launch(void* const* d_in, const int* in_sizes, int n_in,
                              void* d_out, int out_size, void* d_ws, size_t ws_size,
                              hipStream_t stream) {
  const float* x = (const float*)d_in[0];     // (32, 1024, 1024) fp32
  const float* w = (const float*)d_in[1];     // (512, 512) fp32
  float* out = (float*)d_out;                 // (32, 2048, 512) fp32
  uint16_t* wt = (uint16_t*)d_ws;             // 512x512 bf16 = 512 KB scratch

  wt_kernel<<<dim3(16, 16), dim3(32, 8), 0, stream>>>(w, wt);
  gemm_kernel<<<dim3(2048), dim3(256), 0, stream>>>(x, wt, out);
}